// Round 1
// baseline (416.187 us; speedup 1.0000x reference)
//
#include <hip/hip_runtime.h>
#include <hip/hip_bf16.h>

#define BB 16
#define NN 2048
#define FIN 256
#define FO 64

typedef __bf16 bf16x8 __attribute__((ext_vector_type(8)));
typedef float  f32x4  __attribute__((ext_vector_type(4)));
typedef int    i32x4  __attribute__((ext_vector_type(4)));

// ---------------- K1: h GEMM (MFMA bf16) + exact fp32 s_src/s_dst ------------
__global__ __launch_bounds__(256) void k1_gemm(
    const float* __restrict__ x, const float* __restrict__ weight,
    const float* __restrict__ w2,
    __bf16* __restrict__ hT, float* __restrict__ s_src, float* __restrict__ s_dst) {
    __shared__ __bf16 WtL[FO * 264];
    __shared__ float vsL[FIN], vdL[FIN];
    int t = threadIdx.x;
    {
        const float4* wr = (const float4*)(weight + t * FO);
        float a = 0.f, d = 0.f;
#pragma unroll
        for (int c = 0; c < 16; ++c) {
            float4 v = wr[c];
            int o = c * 4;
            WtL[(o + 0) * 264 + t] = (__bf16)v.x;
            WtL[(o + 1) * 264 + t] = (__bf16)v.y;
            WtL[(o + 2) * 264 + t] = (__bf16)v.z;
            WtL[(o + 3) * 264 + t] = (__bf16)v.w;
            a += v.x * w2[o] + v.y * w2[o + 1] + v.z * w2[o + 2] + v.w * w2[o + 3];
            d += v.x * w2[FO + o] + v.y * w2[FO + o + 1] +
                 v.z * w2[FO + o + 2] + v.w * w2[FO + o + 3];
        }
        vsL[t] = a;
        vdL[t] = d;
    }
    __syncthreads();

    int lane = threadIdx.x & 63, w = threadIdx.x >> 6;
    int quad = lane >> 4, m = lane & 15;
    int Rbase = blockIdx.x * 64 + w * 16;
    int R = Rbase + m;
    const float* xr = x + (long)R * FIN;

    f32x4 acc[4] = {};
    float ps = 0.f, pd = 0.f;

#pragma unroll
    for (int k0 = 0; k0 < FIN; k0 += 32) {
        int kb = k0 + quad * 8;
        float4 x0 = *(const float4*)(xr + kb);
        float4 x1 = *(const float4*)(xr + kb + 4);
        float4 u0 = *(const float4*)(vsL + kb);
        float4 u1 = *(const float4*)(vsL + kb + 4);
        float4 t0 = *(const float4*)(vdL + kb);
        float4 t1 = *(const float4*)(vdL + kb + 4);
        ps += x0.x * u0.x + x0.y * u0.y + x0.z * u0.z + x0.w * u0.w +
              x1.x * u1.x + x1.y * u1.y + x1.z * u1.z + x1.w * u1.w;
        pd += x0.x * t0.x + x0.y * t0.y + x0.z * t0.z + x0.w * t0.w +
              x1.x * t1.x + x1.y * t1.y + x1.z * t1.z + x1.w * t1.w;
        bf16x8 bf = {(__bf16)x0.x, (__bf16)x0.y, (__bf16)x0.z, (__bf16)x0.w,
                     (__bf16)x1.x, (__bf16)x1.y, (__bf16)x1.z, (__bf16)x1.w};
#pragma unroll
        for (int ot = 0; ot < 4; ++ot) {
            bf16x8 af = *(const bf16x8*)(WtL + (ot * 16 + m) * 264 + kb);
            acc[ot] = __builtin_amdgcn_mfma_f32_16x16x32_bf16(af, bf, acc[ot], 0, 0, 0);
        }
    }
    ps += __shfl_xor(ps, 16);
    ps += __shfl_xor(ps, 32);
    pd += __shfl_xor(pd, 16);
    pd += __shfl_xor(pd, 32);
    if (quad == 0) {
        s_src[R] = ps;
        s_dst[R] = pd;
    }
    int b = R >> 11;
    int nb = Rbase & (NN - 1);
#pragma unroll
    for (int ot = 0; ot < 4; ++ot) {
#pragma unroll
        for (int r = 0; r < 4; ++r) {
            int o = ot * 16 + quad * 4 + r;
            hT[((long)b * FO + o) * NN + nb + m] = (__bf16)acc[ot][r];
        }
    }
}

// ---------------- K2 v2: barrier-free 1-wave streaming attention -------------
// grid = 16 b * 128 itiles = 2048 blocks of 64 threads (1 wave, 16 i-rows).
// 8 fully-independent waves/CU, ZERO __syncthreads in the main loop, no
// vmcnt(0) drain: the old 4-wave block's per-chunk {issue -> MFMA -> full
// drain -> stage -> barrier} collapsed pipeline depth to 1 chunk and idled
// HBM during stage+barrier+af-build on a 2-block CU. Here each wave
// double-buffers its adj slice in registers (CH=128: 2 x 32 VGPRs) and reads
// hT fragments straight from L2 (4 MB total; XCD-bijective swizzle keeps each
// XCD's 256 blocks on 2 b-slices = 512 KB -> L2-resident), so the adj stream
// never globally stalls. Numerics bit-identical to the previous passing
// kernel: same mx/EL/cK formulation, same j accumulation order.
__global__ __launch_bounds__(64, 2) void k2_attn(
    const int* __restrict__ adj, const float* __restrict__ s_src,
    const float* __restrict__ s_dst, const __bf16* __restrict__ hT,
    float* __restrict__ out) {
    __shared__ float EL[NN];  // 8 KB; 8 blocks/CU -> 64 KB/CU
    int bid = blockIdx.x;
    bid = ((bid & 7) << 8) | (bid >> 3);  // bijective: 2048 = 8 XCD * 256
    int b = bid >> 7;
    int rowbase = (bid & 127) << 4;
    int lane = threadIdx.x & 63;
    int quad = lane >> 4, m = lane & 15;
    int row = rowbase + m;

    // issue adj chunk-0 prefetch FIRST (long pole at startup)
    const i32x4* arow = (const i32x4*)(adj + ((size_t)(b * NN + row)) * NN) + quad * 2;
    i32x4 A0[8], A1[8];
#pragma unroll
    for (int u = 0; u < 4; ++u) {
        A0[2 * u]     = arow[u * 8];
        A0[2 * u + 1] = arow[u * 8 + 1];
    }

    const float* sd = s_dst + b * NN;
    float mx = -3.0e38f;
    for (int j = lane; j < NN; j += 64) mx = fmaxf(mx, sd[j]);
#pragma unroll
    for (int off = 32; off >= 1; off >>= 1) mx = fmaxf(mx, __shfl_xor(mx, off));

    // EL fill, lane-contiguous float4 (conflict-free ds_write_b128)
#pragma unroll
    for (int t = 0; t < 8; ++t) {
        int j0 = t * 256 + lane * 4;
        float4 v = *(const float4*)(sd + j0);
        float4 e;
        e.x = __expf(v.x - mx);
        e.y = __expf(v.y - mx);
        e.z = __expf(v.z - mx);
        e.w = __expf(v.w - mx);
        *(float4*)(EL + j0) = e;
    }
    __syncthreads();  // single wave: just orders ds_write -> ds_read

    float cK = __expf(-(s_src[b * NN + row] + mx));  // relu floor, scaled space

    const float* elp = EL + quad * 8;
    const __bf16* hq = hT + ((long)b * FO + m) * NN + quad * 8;
    const __bf16* hb0 = hq;
    const __bf16* hb1 = hq + 16 * NN;
    const __bf16* hb2 = hq + 32 * NN;
    const __bf16* hb3 = hq + 48 * NN;

    f32x4 acc[4] = {};
    f32x4 accL = {};
    const bf16x8 ones = {(__bf16)1.f, (__bf16)1.f, (__bf16)1.f, (__bf16)1.f,
                         (__bf16)1.f, (__bf16)1.f, (__bf16)1.f, (__bf16)1.f};

// one 128-j chunk: 4 u-steps of {EL ds_read, af build, 1 ones-MFMA + 4 PV-MFMA
// with hT fragments from L2}. All indices static after unroll.
#define COMPUTE(cc, AA)                                                          \
    {                                                                            \
        _Pragma("unroll") for (int u = 0; u < 4; ++u) {                          \
            const float* ep = elp + (cc) * 128 + u * 32;                         \
            float4 e0 = *(const float4*)ep;                                      \
            float4 e1 = *(const float4*)(ep + 4);                                \
            i32x4 a0 = AA[2 * u], a1 = AA[2 * u + 1];                            \
            float p0 = (a0.x > 0) ? fmaxf(e0.x, cK) : 0.f;                       \
            float p1 = (a0.y > 0) ? fmaxf(e0.y, cK) : 0.f;                       \
            float p2 = (a0.z > 0) ? fmaxf(e0.z, cK) : 0.f;                       \
            float p3 = (a0.w > 0) ? fmaxf(e0.w, cK) : 0.f;                       \
            float p4 = (a1.x > 0) ? fmaxf(e1.x, cK) : 0.f;                       \
            float p5 = (a1.y > 0) ? fmaxf(e1.y, cK) : 0.f;                       \
            float p6 = (a1.z > 0) ? fmaxf(e1.z, cK) : 0.f;                       \
            float p7 = (a1.w > 0) ? fmaxf(e1.w, cK) : 0.f;                       \
            bf16x8 af = {(__bf16)p0, (__bf16)p1, (__bf16)p2, (__bf16)p3,         \
                         (__bf16)p4, (__bf16)p5, (__bf16)p6, (__bf16)p7};        \
            accL = __builtin_amdgcn_mfma_f32_16x16x32_bf16(af, ones, accL,       \
                                                           0, 0, 0);             \
            int jo = (cc) * 128 + u * 32;                                        \
            bf16x8 bf0 = *(const bf16x8*)(hb0 + jo);                             \
            acc[0] = __builtin_amdgcn_mfma_f32_16x16x32_bf16(af, bf0, acc[0],    \
                                                             0, 0, 0);           \
            bf16x8 bf1 = *(const bf16x8*)(hb1 + jo);                             \
            acc[1] = __builtin_amdgcn_mfma_f32_16x16x32_bf16(af, bf1, acc[1],    \
                                                             0, 0, 0);           \
            bf16x8 bf2 = *(const bf16x8*)(hb2 + jo);                             \
            acc[2] = __builtin_amdgcn_mfma_f32_16x16x32_bf16(af, bf2, acc[2],    \
                                                             0, 0, 0);           \
            bf16x8 bf3 = *(const bf16x8*)(hb3 + jo);                             \
            acc[3] = __builtin_amdgcn_mfma_f32_16x16x32_bf16(af, bf3, acc[3],    \
                                                             0, 0, 0);           \
        }                                                                        \
    }

    for (int c = 0; c < NN / 128; c += 2) {
        // prefetch chunk c+1 into A1, then compute c from A0
        const i32x4* an = arow + (c + 1) * 32;
#pragma unroll
        for (int u = 0; u < 4; ++u) {
            A1[2 * u]     = an[u * 8];
            A1[2 * u + 1] = an[u * 8 + 1];
        }
        COMPUTE(c, A0);
        // prefetch chunk c+2 into A0, then compute c+1 from A1
        if (c < NN / 128 - 2) {
            const i32x4* an2 = arow + (c + 2) * 32;
#pragma unroll
            for (int u = 0; u < 4; ++u) {
                A0[2 * u]     = an2[u * 8];
                A0[2 * u + 1] = an2[u * 8 + 1];
            }
        }
        COMPUTE(c + 1, A1);
    }
#undef COMPUTE

    // epilogue: D layout col=lane&15 (o), row=quad*4+r (i-local); accL[r]=denom
    float* outp = out + ((long)b * NN + rowbase) * FO;
#pragma unroll
    for (int r = 0; r < 4; ++r) {
        int orow = quad * 4 + r;
        float inv = 1.0f / accL[r];
#pragma unroll
        for (int ot = 0; ot < 4; ++ot) {
            outp[(long)orow * FO + ot * 16 + m] = acc[ot][r] * inv;
        }
    }
}

extern "C" void kernel_launch(void* const* d_in, const int* in_sizes, int n_in,
                              void* d_out, int out_size, void* d_ws, size_t ws_size,
                              hipStream_t stream) {
    const float* x      = (const float*)d_in[0];
    const int*   adj    = (const int*)d_in[1];
    const float* weight = (const float*)d_in[2];
    const float* w2     = (const float*)d_in[3];
    float* out = (float*)d_out;

    char* ws = (char*)d_ws;
    __bf16* hT   = (__bf16*)ws;                              // 4 MB
    float* s_src = (float*)(ws + 4194304);                   // 128 KB
    float* s_dst = (float*)(ws + 4194304 + 131072);          // 128 KB

    k1_gemm<<<512, 256, 0, stream>>>(x, weight, w2, hT, s_src, s_dst);
    k2_attn<<<2048, 64, 0, stream>>>(adj, s_src, s_dst, hT, out);
}

// Round 2
// 414.943 us; speedup vs baseline: 1.0030x; 1.0030x over previous
//
#include <hip/hip_runtime.h>
#include <hip/hip_bf16.h>

#define BB 16
#define NN 2048
#define FIN 256
#define FO 64

typedef __bf16 bf16x8 __attribute__((ext_vector_type(8)));
typedef float  f32x4  __attribute__((ext_vector_type(4)));
typedef int    i32x4  __attribute__((ext_vector_type(4)));

// ---------------- K1: h GEMM (MFMA bf16) + exact fp32 s_src/s_dst ------------
__global__ __launch_bounds__(256) void k1_gemm(
    const float* __restrict__ x, const float* __restrict__ weight,
    const float* __restrict__ w2,
    __bf16* __restrict__ hT, float* __restrict__ s_src, float* __restrict__ s_dst) {
    __shared__ __bf16 WtL[FO * 264];
    __shared__ float vsL[FIN], vdL[FIN];
    int t = threadIdx.x;
    {
        const float4* wr = (const float4*)(weight + t * FO);
        float a = 0.f, d = 0.f;
#pragma unroll
        for (int c = 0; c < 16; ++c) {
            float4 v = wr[c];
            int o = c * 4;
            WtL[(o + 0) * 264 + t] = (__bf16)v.x;
            WtL[(o + 1) * 264 + t] = (__bf16)v.y;
            WtL[(o + 2) * 264 + t] = (__bf16)v.z;
            WtL[(o + 3) * 264 + t] = (__bf16)v.w;
            a += v.x * w2[o] + v.y * w2[o + 1] + v.z * w2[o + 2] + v.w * w2[o + 3];
            d += v.x * w2[FO + o] + v.y * w2[FO + o + 1] +
                 v.z * w2[FO + o + 2] + v.w * w2[FO + o + 3];
        }
        vsL[t] = a;
        vdL[t] = d;
    }
    __syncthreads();

    int lane = threadIdx.x & 63, w = threadIdx.x >> 6;
    int quad = lane >> 4, m = lane & 15;
    int Rbase = blockIdx.x * 64 + w * 16;
    int R = Rbase + m;
    const float* xr = x + (long)R * FIN;

    f32x4 acc[4] = {};
    float ps = 0.f, pd = 0.f;

#pragma unroll
    for (int k0 = 0; k0 < FIN; k0 += 32) {
        int kb = k0 + quad * 8;
        float4 x0 = *(const float4*)(xr + kb);
        float4 x1 = *(const float4*)(xr + kb + 4);
        float4 u0 = *(const float4*)(vsL + kb);
        float4 u1 = *(const float4*)(vsL + kb + 4);
        float4 t0 = *(const float4*)(vdL + kb);
        float4 t1 = *(const float4*)(vdL + kb + 4);
        ps += x0.x * u0.x + x0.y * u0.y + x0.z * u0.z + x0.w * u0.w +
              x1.x * u1.x + x1.y * u1.y + x1.z * u1.z + x1.w * u1.w;
        pd += x0.x * t0.x + x0.y * t0.y + x0.z * t0.z + x0.w * t0.w +
              x1.x * t1.x + x1.y * t1.y + x1.z * t1.z + x1.w * t1.w;
        bf16x8 bf = {(__bf16)x0.x, (__bf16)x0.y, (__bf16)x0.z, (__bf16)x0.w,
                     (__bf16)x1.x, (__bf16)x1.y, (__bf16)x1.z, (__bf16)x1.w};
#pragma unroll
        for (int ot = 0; ot < 4; ++ot) {
            bf16x8 af = *(const bf16x8*)(WtL + (ot * 16 + m) * 264 + kb);
            acc[ot] = __builtin_amdgcn_mfma_f32_16x16x32_bf16(af, bf, acc[ot], 0, 0, 0);
        }
    }
    ps += __shfl_xor(ps, 16);
    ps += __shfl_xor(ps, 32);
    pd += __shfl_xor(pd, 16);
    pd += __shfl_xor(pd, 32);
    if (quad == 0) {
        s_src[R] = ps;
        s_dst[R] = pd;
    }
    int b = R >> 11;
    int nb = Rbase & (NN - 1);
#pragma unroll
    for (int ot = 0; ot < 4; ++ot) {
#pragma unroll
        for (int r = 0; r < 4; ++r) {
            int o = ot * 16 + quad * 4 + r;
            hT[((long)b * FO + o) * NN + nb + m] = (__bf16)acc[ot][r];
        }
    }
}

// ---------------- K2 v3: 4-wave block, shared EL, NO main-loop barrier -------
// v1's structure (512 blocks x 256 thr, EL amortized over 4 waves) minus the
// per-chunk {vmcnt(0) drain + __syncthreads}: hT b-fragments read directly
// (4 MB; XCD-bijective swizzle -> 512 KB per XCD -> L2-resident), adj
// register-double-buffered in 128-j chunks so each wave holds ~8 KB of HBM
// loads in flight at all times. launch_bounds(256,3) caps VGPR at 168 ->
// 3 blocks/CU = 12 waves/CU (1.5x v1) with zero global sync points after the
// EL barrier. Numerics bit-identical to v1: same mx/EL/cK formulation, same
// MFMA j-order (af[u] over j ascending), same bf16 roundings.
__global__ __launch_bounds__(256, 3) void k2_attn(
    const int* __restrict__ adj, const float* __restrict__ s_src,
    const float* __restrict__ s_dst, const __bf16* __restrict__ hT,
    float* __restrict__ out) {
    __shared__ float EL[NN];  // 8 KB; 3 blocks/CU -> 24 KB/CU
    int bid = blockIdx.x;
    bid = ((bid & 7) << 6) | (bid >> 3);  // bijective: 512 = 8 XCD * 64
    int b = bid >> 5;
    int i0 = (bid & 31) << 6;
    int lane = threadIdx.x & 63, w = threadIdx.x >> 6;
    int quad = lane >> 4, m = lane & 15;
    int rowbase = i0 + w * 16;
    int row = rowbase + m;

    // issue adj chunk-0 prefetch FIRST (long pole at startup)
    const i32x4* arow = (const i32x4*)(adj + ((size_t)(b * NN + row)) * NN) + quad * 2;
    i32x4 A0[8], A1[8];
#pragma unroll
    for (int u = 0; u < 4; ++u) {
        A0[2 * u]     = arow[u * 8];
        A0[2 * u + 1] = arow[u * 8 + 1];
    }

    const float* sd = s_dst + b * NN;
    // per-wave mx (bitwise-identical across waves) — exactly v1's formulation
    float mx = -3.0e38f;
    for (int j = lane; j < NN; j += 64) mx = fmaxf(mx, sd[j]);
#pragma unroll
    for (int off = 32; off >= 1; off >>= 1) mx = fmaxf(mx, __shfl_xor(mx, off));
    // cooperative EL fill — exactly v1's indexing (256 threads x 8)
    {
        int j0 = threadIdx.x * 8;
        float4 v0 = *(const float4*)(sd + j0);
        float4 v1 = *(const float4*)(sd + j0 + 4);
        EL[j0 + 0] = __expf(v0.x - mx);
        EL[j0 + 1] = __expf(v0.y - mx);
        EL[j0 + 2] = __expf(v0.z - mx);
        EL[j0 + 3] = __expf(v0.w - mx);
        EL[j0 + 4] = __expf(v1.x - mx);
        EL[j0 + 5] = __expf(v1.y - mx);
        EL[j0 + 6] = __expf(v1.z - mx);
        EL[j0 + 7] = __expf(v1.w - mx);
    }
    __syncthreads();  // the ONLY block barrier: EL visible to all 4 waves

    float cK = __expf(-(s_src[b * NN + row] + mx));  // relu floor, scaled space

    const float* elp = EL + quad * 8;
    const __bf16* hq = hT + ((long)b * FO + m) * NN + quad * 8;
    const __bf16* hb0 = hq;
    const __bf16* hb1 = hq + 16 * NN;
    const __bf16* hb2 = hq + 32 * NN;
    const __bf16* hb3 = hq + 48 * NN;

    f32x4 acc[4] = {};
    f32x4 accL = {};
    const bf16x8 ones = {(__bf16)1.f, (__bf16)1.f, (__bf16)1.f, (__bf16)1.f,
                         (__bf16)1.f, (__bf16)1.f, (__bf16)1.f, (__bf16)1.f};

// one 128-j chunk: 4 u-steps of {EL ds_read (quad-broadcast), af build,
// 1 ones-MFMA + 4 PV-MFMA with hT fragments from L2}. Static after unroll.
#define COMPUTE(cc, AA)                                                          \
    {                                                                            \
        _Pragma("unroll") for (int u = 0; u < 4; ++u) {                          \
            const float* ep = elp + (cc) * 128 + u * 32;                         \
            float4 e0 = *(const float4*)ep;                                      \
            float4 e1 = *(const float4*)(ep + 4);                                \
            i32x4 a0 = AA[2 * u], a1 = AA[2 * u + 1];                            \
            float p0 = (a0.x > 0) ? fmaxf(e0.x, cK) : 0.f;                       \
            float p1 = (a0.y > 0) ? fmaxf(e0.y, cK) : 0.f;                       \
            float p2 = (a0.z > 0) ? fmaxf(e0.z, cK) : 0.f;                       \
            float p3 = (a0.w > 0) ? fmaxf(e0.w, cK) : 0.f;                       \
            float p4 = (a1.x > 0) ? fmaxf(e1.x, cK) : 0.f;                       \
            float p5 = (a1.y > 0) ? fmaxf(e1.y, cK) : 0.f;                       \
            float p6 = (a1.z > 0) ? fmaxf(e1.z, cK) : 0.f;                       \
            float p7 = (a1.w > 0) ? fmaxf(e1.w, cK) : 0.f;                       \
            bf16x8 af = {(__bf16)p0, (__bf16)p1, (__bf16)p2, (__bf16)p3,         \
                         (__bf16)p4, (__bf16)p5, (__bf16)p6, (__bf16)p7};        \
            accL = __builtin_amdgcn_mfma_f32_16x16x32_bf16(af, ones, accL,       \
                                                           0, 0, 0);             \
            int jo = (cc) * 128 + u * 32;                                        \
            bf16x8 bf0 = *(const bf16x8*)(hb0 + jo);                             \
            acc[0] = __builtin_amdgcn_mfma_f32_16x16x32_bf16(af, bf0, acc[0],    \
                                                             0, 0, 0);           \
            bf16x8 bf1 = *(const bf16x8*)(hb1 + jo);                             \
            acc[1] = __builtin_amdgcn_mfma_f32_16x16x32_bf16(af, bf1, acc[1],    \
                                                             0, 0, 0);           \
            bf16x8 bf2 = *(const bf16x8*)(hb2 + jo);                             \
            acc[2] = __builtin_amdgcn_mfma_f32_16x16x32_bf16(af, bf2, acc[2],    \
                                                             0, 0, 0);           \
            bf16x8 bf3 = *(const bf16x8*)(hb3 + jo);                             \
            acc[3] = __builtin_amdgcn_mfma_f32_16x16x32_bf16(af, bf3, acc[3],    \
                                                             0, 0, 0);           \
        }                                                                        \
    }

    for (int c = 0; c < NN / 128; c += 2) {
        // prefetch chunk c+1 into A1, then compute c from A0
        const i32x4* an = arow + (c + 1) * 32;
#pragma unroll
        for (int u = 0; u < 4; ++u) {
            A1[2 * u]     = an[u * 8];
            A1[2 * u + 1] = an[u * 8 + 1];
        }
        COMPUTE(c, A0);
        // prefetch chunk c+2 into A0, then compute c+1 from A1
        if (c < NN / 128 - 2) {
            const i32x4* an2 = arow + (c + 2) * 32;
#pragma unroll
            for (int u = 0; u < 4; ++u) {
                A0[2 * u]     = an2[u * 8];
                A0[2 * u + 1] = an2[u * 8 + 1];
            }
        }
        COMPUTE(c + 1, A1);
    }
#undef COMPUTE

    // epilogue: D layout col=lane&15 (o), row=quad*4+r (i-local); accL[r]=denom
    float* outp = out + ((long)b * NN + rowbase) * FO;
#pragma unroll
    for (int r = 0; r < 4; ++r) {
        int orow = quad * 4 + r;
        float inv = 1.0f / accL[r];
#pragma unroll
        for (int ot = 0; ot < 4; ++ot) {
            outp[(long)orow * FO + ot * 16 + m] = acc[ot][r] * inv;
        }
    }
}

extern "C" void kernel_launch(void* const* d_in, const int* in_sizes, int n_in,
                              void* d_out, int out_size, void* d_ws, size_t ws_size,
                              hipStream_t stream) {
    const float* x      = (const float*)d_in[0];
    const int*   adj    = (const int*)d_in[1];
    const float* weight = (const float*)d_in[2];
    const float* w2     = (const float*)d_in[3];
    float* out = (float*)d_out;

    char* ws = (char*)d_ws;
    __bf16* hT   = (__bf16*)ws;                              // 4 MB
    float* s_src = (float*)(ws + 4194304);                   // 128 KB
    float* s_dst = (float*)(ws + 4194304 + 131072);          // 128 KB

    k1_gemm<<<512, 256, 0, stream>>>(x, weight, w2, hT, s_src, s_dst);
    k2_attn<<<512, 256, 0, stream>>>(adj, s_src, s_dst, hT, out);
}

// Round 3
// 398.642 us; speedup vs baseline: 1.0440x; 1.0409x over previous
//
#include <hip/hip_runtime.h>
#include <hip/hip_bf16.h>

#define BB 16
#define NN 2048
#define FIN 256
#define FO 64
#define CH 128        // k2 j-chunk (halved vs v1: LDS 43 KB -> 3 blocks/CU)
#define HSTR 136      // hL row stride (bf16): 272 B => 4m%32 banks, 2-way free

typedef __bf16 bf16x8 __attribute__((ext_vector_type(8)));
typedef float  f32x4  __attribute__((ext_vector_type(4)));
typedef int    i32x4  __attribute__((ext_vector_type(4)));

// ---------------- K1: h GEMM (MFMA bf16) + exact fp32 s_src/s_dst ------------
__global__ __launch_bounds__(256) void k1_gemm(
    const float* __restrict__ x, const float* __restrict__ weight,
    const float* __restrict__ w2,
    __bf16* __restrict__ hT, float* __restrict__ s_src, float* __restrict__ s_dst) {
    __shared__ __bf16 WtL[FO * 264];
    __shared__ float vsL[FIN], vdL[FIN];
    int t = threadIdx.x;
    {
        const float4* wr = (const float4*)(weight + t * FO);
        float a = 0.f, d = 0.f;
#pragma unroll
        for (int c = 0; c < 16; ++c) {
            float4 v = wr[c];
            int o = c * 4;
            WtL[(o + 0) * 264 + t] = (__bf16)v.x;
            WtL[(o + 1) * 264 + t] = (__bf16)v.y;
            WtL[(o + 2) * 264 + t] = (__bf16)v.z;
            WtL[(o + 3) * 264 + t] = (__bf16)v.w;
            a += v.x * w2[o] + v.y * w2[o + 1] + v.z * w2[o + 2] + v.w * w2[o + 3];
            d += v.x * w2[FO + o] + v.y * w2[FO + o + 1] +
                 v.z * w2[FO + o + 2] + v.w * w2[FO + o + 3];
        }
        vsL[t] = a;
        vdL[t] = d;
    }
    __syncthreads();

    int lane = threadIdx.x & 63, w = threadIdx.x >> 6;
    int quad = lane >> 4, m = lane & 15;
    int Rbase = blockIdx.x * 64 + w * 16;
    int R = Rbase + m;
    const float* xr = x + (long)R * FIN;

    f32x4 acc[4] = {};
    float ps = 0.f, pd = 0.f;

#pragma unroll
    for (int k0 = 0; k0 < FIN; k0 += 32) {
        int kb = k0 + quad * 8;
        float4 x0 = *(const float4*)(xr + kb);
        float4 x1 = *(const float4*)(xr + kb + 4);
        float4 u0 = *(const float4*)(vsL + kb);
        float4 u1 = *(const float4*)(vsL + kb + 4);
        float4 t0 = *(const float4*)(vdL + kb);
        float4 t1 = *(const float4*)(vdL + kb + 4);
        ps += x0.x * u0.x + x0.y * u0.y + x0.z * u0.z + x0.w * u0.w +
              x1.x * u1.x + x1.y * u1.y + x1.z * u1.z + x1.w * u1.w;
        pd += x0.x * t0.x + x0.y * t0.y + x0.z * t0.z + x0.w * t0.w +
              x1.x * t1.x + x1.y * t1.y + x1.z * t1.z + x1.w * t1.w;
        bf16x8 bf = {(__bf16)x0.x, (__bf16)x0.y, (__bf16)x0.z, (__bf16)x0.w,
                     (__bf16)x1.x, (__bf16)x1.y, (__bf16)x1.z, (__bf16)x1.w};
#pragma unroll
        for (int ot = 0; ot < 4; ++ot) {
            bf16x8 af = *(const bf16x8*)(WtL + (ot * 16 + m) * 264 + kb);
            acc[ot] = __builtin_amdgcn_mfma_f32_16x16x32_bf16(af, bf, acc[ot], 0, 0, 0);
        }
    }
    ps += __shfl_xor(ps, 16);
    ps += __shfl_xor(ps, 32);
    pd += __shfl_xor(pd, 16);
    pd += __shfl_xor(pd, 32);
    if (quad == 0) {
        s_src[R] = ps;
        s_dst[R] = pd;
    }
    int b = R >> 11;
    int nb = Rbase & (NN - 1);
#pragma unroll
    for (int ot = 0; ot < 4; ++ot) {
#pragma unroll
        for (int r = 0; r < 4; ++r) {
            int o = ot * 16 + quad * 4 + r;
            hT[((long)b * FO + o) * NN + nb + m] = (__bf16)acc[ot][r];
        }
    }
}

// ---------------- K2 v4: v1 structure, CH=128 -> 3 blocks/CU ------------------
// v2/v3 post-mortem: hT-from-L2 regressed 21 us because hT fragment loads
// share the in-order vmcnt counter with the adj prefetch stream — consuming a
// fragment drains the whole prefetch. v1's LDS staging keeps fragment reads on
// lgkmcnt (decoupled). Kept here. The remaining v1 stall is the per-chunk
// __syncthreads vmcnt(0) drain with only 2 blocks/CU (74 KB LDS): both
// resident blocks can align their zero-outstanding windows. Fix: CH 256->128
// shrinks hL to 2 x 17 KB; total LDS 43 KB -> 3 blocks/CU = 12 waves/CU with
// independent barrier cadences (when one block drains, two still stream), and
// per-drain magnitude halves. launch_bounds(256,3) caps VGPR at 168 (est.
// ~130, no spill). Numerics bit-identical to v1: same kstep j-order, same
// u-ascending MFMA accumulate order, same mx/EL/cK formulation.
__global__ __launch_bounds__(256, 3) void k2_attn(
    const int* __restrict__ adj, const float* __restrict__ s_src,
    const float* __restrict__ s_dst, const __bf16* __restrict__ hT,
    float* __restrict__ out) {
    __shared__ __bf16 hL[2][FO * HSTR];  // 2 x 17 KB
    __shared__ float EL[NN];             // 8 KB
    int b = blockIdx.x >> 5;
    int i0 = (blockIdx.x & 31) << 6;
    int lane = threadIdx.x & 63, w = threadIdx.x >> 6;
    int quad = lane >> 4, m = lane & 15;
    int rowbase = i0 + w * 16;
    int row = rowbase + m;

    const float* sd = s_dst + b * NN;
    // per-wave mx (bitwise-identical across waves)
    float mx = -3.0e38f;
    for (int j = lane; j < NN; j += 64) mx = fmaxf(mx, sd[j]);
#pragma unroll
    for (int off = 32; off >= 1; off >>= 1) mx = fmaxf(mx, __shfl_xor(mx, off));
    // cooperative EL fill (visible after the initial __syncthreads)
    {
        int j0 = threadIdx.x * 8;
        float4 v0 = *(const float4*)(sd + j0);
        float4 v1 = *(const float4*)(sd + j0 + 4);
        EL[j0 + 0] = __expf(v0.x - mx);
        EL[j0 + 1] = __expf(v0.y - mx);
        EL[j0 + 2] = __expf(v0.z - mx);
        EL[j0 + 3] = __expf(v0.w - mx);
        EL[j0 + 4] = __expf(v1.x - mx);
        EL[j0 + 5] = __expf(v1.y - mx);
        EL[j0 + 6] = __expf(v1.z - mx);
        EL[j0 + 7] = __expf(v1.w - mx);
    }

    float cK = __expf(-(s_src[b * NN + row] + mx));  // relu floor, scaled space

    // adj base for this lane's row; per chunk c, kstep u covers j-units
    // c*32 + u*8 + quad*2 (i32x4 units of 4 ints)
    const i32x4* arow = (const i32x4*)(adj + ((size_t)(b * NN + row)) * NN);
    int aq = quad * 2;

    // hT staging role: thread stages o-row (tid>>2), 64 B at col (tid&3)*32
    int so = threadIdx.x >> 2;
    int sc = (threadIdx.x & 3) * 32;
    const __bf16* hsrc = hT + ((long)b * FO + so) * NN + sc;
    int ldoff = so * HSTR + sc;
    int q8 = quad * 8;

    // ---- prefetch chunk 0: adj (8 x i32x4) + hT (4 x bf16x8) ----
    i32x4 A[8];
#pragma unroll
    for (int u = 0; u < 4; ++u) {
        A[2 * u]     = arow[u * 8 + aq];
        A[2 * u + 1] = arow[u * 8 + aq + 1];
    }
    bf16x8 st[4];
    {
        const bf16x8* sp = (const bf16x8*)hsrc;
#pragma unroll
        for (int i = 0; i < 4; ++i) st[i] = sp[i];
    }
    {
        bf16x8* dp = (bf16x8*)(hL[0] + ldoff);
#pragma unroll
        for (int i = 0; i < 4; ++i) dp[i] = st[i];
    }
    __syncthreads();  // buf0 + EL visible

    f32x4 acc[4] = {};
    f32x4 accL = {};
    const bf16x8 ones = {(__bf16)1.f, (__bf16)1.f, (__bf16)1.f, (__bf16)1.f,
                         (__bf16)1.f, (__bf16)1.f, (__bf16)1.f, (__bf16)1.f};

    for (int c = 0; c < NN / CH; ++c) {
        const __bf16* cur = hL[c & 1];
        // ---- build all A-fragments for chunk c from adj regs + EL ----
        bf16x8 af[4];
#pragma unroll
        for (int u = 0; u < 4; ++u) {
            const float* ep = EL + (c * 4 + u) * 32 + q8;
            float4 e0 = *(const float4*)ep;
            float4 e1 = *(const float4*)(ep + 4);
            i32x4 a0 = A[2 * u], a1 = A[2 * u + 1];
            float p0 = (a0.x > 0) ? fmaxf(e0.x, cK) : 0.f;
            float p1 = (a0.y > 0) ? fmaxf(e0.y, cK) : 0.f;
            float p2 = (a0.z > 0) ? fmaxf(e0.z, cK) : 0.f;
            float p3 = (a0.w > 0) ? fmaxf(e0.w, cK) : 0.f;
            float p4 = (a1.x > 0) ? fmaxf(e1.x, cK) : 0.f;
            float p5 = (a1.y > 0) ? fmaxf(e1.y, cK) : 0.f;
            float p6 = (a1.z > 0) ? fmaxf(e1.z, cK) : 0.f;
            float p7 = (a1.w > 0) ? fmaxf(e1.w, cK) : 0.f;
            af[u] = bf16x8{(__bf16)p0, (__bf16)p1, (__bf16)p2, (__bf16)p3,
                           (__bf16)p4, (__bf16)p5, (__bf16)p6, (__bf16)p7};
        }
        // ---- issue chunk c+1 prefetches (adj regs now free; consumed below) --
        if (c < NN / CH - 1) {
            const i32x4* an = arow + (c + 1) * 32;
#pragma unroll
            for (int u = 0; u < 4; ++u) {
                A[2 * u]     = an[u * 8 + aq];
                A[2 * u + 1] = an[u * 8 + aq + 1];
            }
            const bf16x8* sp = (const bf16x8*)(hsrc + (c + 1) * CH);
#pragma unroll
            for (int i = 0; i < 4; ++i) st[i] = sp[i];
        }
        // ---- MFMA phase chunk c ----
#pragma unroll
        for (int u = 0; u < 4; ++u) {
            accL = __builtin_amdgcn_mfma_f32_16x16x32_bf16(af[u], ones, accL, 0, 0, 0);
            const __bf16* hb = cur + u * 32 + q8;
#pragma unroll
            for (int ot = 0; ot < 4; ++ot) {
                bf16x8 bf = *(const bf16x8*)(hb + (ot * 16 + m) * HSTR);
                acc[ot] = __builtin_amdgcn_mfma_f32_16x16x32_bf16(af[u], bf, acc[ot], 0, 0, 0);
            }
        }
        // ---- stage chunk c+1 into the other buffer, then one barrier ----
        if (c < NN / CH - 1) {
            bf16x8* dp = (bf16x8*)(hL[(c + 1) & 1] + ldoff);
#pragma unroll
            for (int i = 0; i < 4; ++i) dp[i] = st[i];
        }
        __syncthreads();
    }

    // epilogue: D layout col=lane&15 (o), row=quad*4+r (i-local); accL[r]=denom
    float* outp = out + ((long)b * NN + rowbase) * FO;
#pragma unroll
    for (int r = 0; r < 4; ++r) {
        int orow = quad * 4 + r;
        float inv = 1.0f / accL[r];
#pragma unroll
        for (int ot = 0; ot < 4; ++ot) {
            outp[(long)orow * FO + ot * 16 + m] = acc[ot][r] * inv;
        }
    }
}

extern "C" void kernel_launch(void* const* d_in, const int* in_sizes, int n_in,
                              void* d_out, int out_size, void* d_ws, size_t ws_size,
                              hipStream_t stream) {
    const float* x      = (const float*)d_in[0];
    const int*   adj    = (const int*)d_in[1];
    const float* weight = (const float*)d_in[2];
    const float* w2     = (const float*)d_in[3];
    float* out = (float*)d_out;

    char* ws = (char*)d_ws;
    __bf16* hT   = (__bf16*)ws;                              // 4 MB
    float* s_src = (float*)(ws + 4194304);                   // 128 KB
    float* s_dst = (float*)(ws + 4194304 + 131072);          // 128 KB

    k1_gemm<<<512, 256, 0, stream>>>(x, weight, w2, hT, s_src, s_dst);
    k2_attn<<<512, 256, 0, stream>>>(adj, s_src, s_dst, hT, out);
}

// Round 4
// 397.605 us; speedup vs baseline: 1.0467x; 1.0026x over previous
//
#include <hip/hip_runtime.h>
#include <hip/hip_bf16.h>

#define BB 16
#define NN 2048
#define FIN 256
#define FO 64
#define CH 128        // k2 j-chunk; LDS 43 KB -> 3 blocks/CU
#define HSTR 136      // hL row stride (bf16), CH+8 pad (same as v4)
#define NCH (NN / CH) // 16 chunks

typedef __bf16 bf16x8 __attribute__((ext_vector_type(8)));
typedef float  f32x4  __attribute__((ext_vector_type(4)));
typedef int    i32x4  __attribute__((ext_vector_type(4)));

// ---------------- K1: h GEMM (MFMA bf16) + exact fp32 s_src/s_dst ------------
__global__ __launch_bounds__(256) void k1_gemm(
    const float* __restrict__ x, const float* __restrict__ weight,
    const float* __restrict__ w2,
    __bf16* __restrict__ hT, float* __restrict__ s_src, float* __restrict__ s_dst) {
    __shared__ __bf16 WtL[FO * 264];
    __shared__ float vsL[FIN], vdL[FIN];
    int t = threadIdx.x;
    {
        const float4* wr = (const float4*)(weight + t * FO);
        float a = 0.f, d = 0.f;
#pragma unroll
        for (int c = 0; c < 16; ++c) {
            float4 v = wr[c];
            int o = c * 4;
            WtL[(o + 0) * 264 + t] = (__bf16)v.x;
            WtL[(o + 1) * 264 + t] = (__bf16)v.y;
            WtL[(o + 2) * 264 + t] = (__bf16)v.z;
            WtL[(o + 3) * 264 + t] = (__bf16)v.w;
            a += v.x * w2[o] + v.y * w2[o + 1] + v.z * w2[o + 2] + v.w * w2[o + 3];
            d += v.x * w2[FO + o] + v.y * w2[FO + o + 1] +
                 v.z * w2[FO + o + 2] + v.w * w2[FO + o + 3];
        }
        vsL[t] = a;
        vdL[t] = d;
    }
    __syncthreads();

    int lane = threadIdx.x & 63, w = threadIdx.x >> 6;
    int quad = lane >> 4, m = lane & 15;
    int Rbase = blockIdx.x * 64 + w * 16;
    int R = Rbase + m;
    const float* xr = x + (long)R * FIN;

    f32x4 acc[4] = {};
    float ps = 0.f, pd = 0.f;

#pragma unroll
    for (int k0 = 0; k0 < FIN; k0 += 32) {
        int kb = k0 + quad * 8;
        float4 x0 = *(const float4*)(xr + kb);
        float4 x1 = *(const float4*)(xr + kb + 4);
        float4 u0 = *(const float4*)(vsL + kb);
        float4 u1 = *(const float4*)(vsL + kb + 4);
        float4 t0 = *(const float4*)(vdL + kb);
        float4 t1 = *(const float4*)(vdL + kb + 4);
        ps += x0.x * u0.x + x0.y * u0.y + x0.z * u0.z + x0.w * u0.w +
              x1.x * u1.x + x1.y * u1.y + x1.z * u1.z + x1.w * u1.w;
        pd += x0.x * t0.x + x0.y * t0.y + x0.z * t0.z + x0.w * t0.w +
              x1.x * t1.x + x1.y * t1.y + x1.z * t1.z + x1.w * t1.w;
        bf16x8 bf = {(__bf16)x0.x, (__bf16)x0.y, (__bf16)x0.z, (__bf16)x0.w,
                     (__bf16)x1.x, (__bf16)x1.y, (__bf16)x1.z, (__bf16)x1.w};
#pragma unroll
        for (int ot = 0; ot < 4; ++ot) {
            bf16x8 af = *(const bf16x8*)(WtL + (ot * 16 + m) * 264 + kb);
            acc[ot] = __builtin_amdgcn_mfma_f32_16x16x32_bf16(af, bf, acc[ot], 0, 0, 0);
        }
    }
    ps += __shfl_xor(ps, 16);
    ps += __shfl_xor(ps, 32);
    pd += __shfl_xor(pd, 16);
    pd += __shfl_xor(pd, 32);
    if (quad == 0) {
        s_src[R] = ps;
        s_dst[R] = pd;
    }
    int b = R >> 11;
    int nb = Rbase & (NN - 1);
#pragma unroll
    for (int ot = 0; ot < 4; ++ot) {
#pragma unroll
        for (int r = 0; r < 4; ++r) {
            int o = ot * 16 + quad * 4 + r;
            hT[((long)b * FO + o) * NN + nb + m] = (__bf16)acc[ot][r];
        }
    }
}

// ---------------- K2 v5: counted-vmcnt pipeline, vmcnt never drains ----------
// v1-v4 post-mortem: the single in-order vmcnt counter + issue order
// {adj then hT} meant the stage ds_write (needs hT) drained the whole adj
// prefetch every chunk — pipeline depth 1 regardless of barriers/occupancy.
// v5: (1) hT issued FIRST, adj second -> stage waits at vmcnt(8), the 8 adj
// loads stay in flight across the barrier; (2) adj 2 chunks deep (A0/A1,
// static idx via 2-unrolled loop) so af-build consumes loads issued 2
// chunk-times ago; (3) raw s_barrier + lgkmcnt(0)-only (cross-wave hazards
// are LDS-only: hL dbuf + EL; no cross-wave global communication, so the
// __syncthreads vmcnt(0) drain was never needed); (4) loads unconditional
// with clamped chunk indices -> constant load counts, counted compiler
// waits on every path. Numerics bit-identical to v4: same j-order, same
// u-ascending MFMA accumulate order, same mx/EL/cK formulation.
__global__ __launch_bounds__(256, 3) void k2_attn(
    const int* __restrict__ adj, const float* __restrict__ s_src,
    const float* __restrict__ s_dst, const __bf16* __restrict__ hT,
    float* __restrict__ out) {
    __shared__ __bf16 hL[2][FO * HSTR];  // 2 x 17 KB
    __shared__ float EL[NN];             // 8 KB
    int b = blockIdx.x >> 5;
    int i0 = (blockIdx.x & 31) << 6;
    int lane = threadIdx.x & 63, w = threadIdx.x >> 6;
    int quad = lane >> 4, m = lane & 15;
    int rowbase = i0 + w * 16;
    int row = rowbase + m;

    // adj base for this lane's row; chunk c covers i32x4 units c*32 .. +31
    const i32x4* arow = (const i32x4*)(adj + ((size_t)(b * NN + row)) * NN);
    int aq = quad * 2;

    // hT staging role: thread stages o-row (tid>>2), 64 B at col (tid&3)*32
    int so = threadIdx.x >> 2;
    int sc = (threadIdx.x & 3) * 32;
    const __bf16* hsrc = hT + ((long)b * FO + so) * NN + sc;
    int ldoff = so * HSTR + sc;
    int q8 = quad * 8;

    // ---- prologue prefetch: hT(0) FIRST, then adj(0), adj(1) ----
    bf16x8 st[4];
    {
        const bf16x8* sp = (const bf16x8*)hsrc;
#pragma unroll
        for (int i = 0; i < 4; ++i) st[i] = sp[i];
    }
    i32x4 A0[8], A1[8];
#pragma unroll
    for (int u = 0; u < 4; ++u) {
        A0[2 * u]     = arow[u * 8 + aq];
        A0[2 * u + 1] = arow[u * 8 + aq + 1];
    }
#pragma unroll
    for (int u = 0; u < 4; ++u) {
        A1[2 * u]     = arow[32 + u * 8 + aq];
        A1[2 * u + 1] = arow[32 + u * 8 + aq + 1];
    }

    const float* sd = s_dst + b * NN;
    // per-wave mx (bitwise-identical across waves)
    float mx = -3.0e38f;
    for (int j = lane; j < NN; j += 64) mx = fmaxf(mx, sd[j]);
#pragma unroll
    for (int off = 32; off >= 1; off >>= 1) mx = fmaxf(mx, __shfl_xor(mx, off));
    // cooperative EL fill
    {
        int j0 = threadIdx.x * 8;
        float4 v0 = *(const float4*)(sd + j0);
        float4 v1 = *(const float4*)(sd + j0 + 4);
        EL[j0 + 0] = __expf(v0.x - mx);
        EL[j0 + 1] = __expf(v0.y - mx);
        EL[j0 + 2] = __expf(v0.z - mx);
        EL[j0 + 3] = __expf(v0.w - mx);
        EL[j0 + 4] = __expf(v1.x - mx);
        EL[j0 + 5] = __expf(v1.y - mx);
        EL[j0 + 6] = __expf(v1.z - mx);
        EL[j0 + 7] = __expf(v1.w - mx);
    }

    float cK = __expf(-(s_src[b * NN + row] + mx));  // relu floor, scaled space

    // stage hT(0) into buf0; compiler waits only the st dep (counted vmcnt)
    {
        bf16x8* dp = (bf16x8*)(hL[0] + ldoff);
#pragma unroll
        for (int i = 0; i < 4; ++i) dp[i] = st[i];
    }
    asm volatile("s_waitcnt lgkmcnt(0)" ::: "memory");
    __builtin_amdgcn_s_barrier();  // buf0 + EL visible; NO vmcnt drain

    f32x4 acc[4] = {};
    f32x4 accL = {};
    const bf16x8 ones = {(__bf16)1.f, (__bf16)1.f, (__bf16)1.f, (__bf16)1.f,
                         (__bf16)1.f, (__bf16)1.f, (__bf16)1.f, (__bf16)1.f};

// One chunk: af-build (consumes AA, issued 2 chunks ago) -> issue hT(cc+1)
// then adj(cc+2) into AA (clamped, unconditional) -> MFMA on hL[cc&1] ->
// stage hT into hL[(cc+1)&1] (waits vmcnt(8): adj stays in flight) ->
// lgkmcnt(0) + raw barrier. vmcnt never reaches 0 in steady state.
#define CHUNK(cc, AA)                                                            \
    {                                                                            \
        const __bf16* cur = hL[(cc) & 1];                                        \
        bf16x8 af[4];                                                            \
        _Pragma("unroll") for (int u = 0; u < 4; ++u) {                          \
            const float* ep = EL + ((cc) * 4 + u) * 32 + q8;                     \
            float4 e0 = *(const float4*)ep;                                      \
            float4 e1 = *(const float4*)(ep + 4);                                \
            i32x4 a0 = AA[2 * u], a1 = AA[2 * u + 1];                            \
            float p0 = (a0.x > 0) ? fmaxf(e0.x, cK) : 0.f;                       \
            float p1 = (a0.y > 0) ? fmaxf(e0.y, cK) : 0.f;                       \
            float p2 = (a0.z > 0) ? fmaxf(e0.z, cK) : 0.f;                       \
            float p3 = (a0.w > 0) ? fmaxf(e0.w, cK) : 0.f;                       \
            float p4 = (a1.x > 0) ? fmaxf(e1.x, cK) : 0.f;                       \
            float p5 = (a1.y > 0) ? fmaxf(e1.y, cK) : 0.f;                       \
            float p6 = (a1.z > 0) ? fmaxf(e1.z, cK) : 0.f;                       \
            float p7 = (a1.w > 0) ? fmaxf(e1.w, cK) : 0.f;                       \
            af[u] = bf16x8{(__bf16)p0, (__bf16)p1, (__bf16)p2, (__bf16)p3,       \
                           (__bf16)p4, (__bf16)p5, (__bf16)p6, (__bf16)p7};      \
        }                                                                        \
        {                                                                        \
            int cn = ((cc) + 1 < NCH) ? (cc) + 1 : NCH - 1;                      \
            int ca = ((cc) + 2 < NCH) ? (cc) + 2 : NCH - 1;                      \
            const bf16x8* sp = (const bf16x8*)(hsrc + cn * CH);                  \
            _Pragma("unroll") for (int i = 0; i < 4; ++i) st[i] = sp[i];         \
            const i32x4* an = arow + ca * 32;                                    \
            _Pragma("unroll") for (int u = 0; u < 4; ++u) {                      \
                AA[2 * u]     = an[u * 8 + aq];                                  \
                AA[2 * u + 1] = an[u * 8 + aq + 1];                              \
            }                                                                    \
        }                                                                        \
        _Pragma("unroll") for (int u = 0; u < 4; ++u) {                          \
            accL = __builtin_amdgcn_mfma_f32_16x16x32_bf16(af[u], ones, accL,    \
                                                           0, 0, 0);             \
            const __bf16* hb = cur + u * 32 + q8;                                \
            _Pragma("unroll") for (int ot = 0; ot < 4; ++ot) {                   \
                bf16x8 bf = *(const bf16x8*)(hb + (ot * 16 + m) * HSTR);         \
                acc[ot] = __builtin_amdgcn_mfma_f32_16x16x32_bf16(af[u], bf,     \
                                                                  acc[ot],       \
                                                                  0, 0, 0);      \
            }                                                                    \
        }                                                                        \
        {                                                                        \
            bf16x8* dp = (bf16x8*)(hL[((cc) + 1) & 1] + ldoff);                  \
            _Pragma("unroll") for (int i = 0; i < 4; ++i) dp[i] = st[i];         \
        }                                                                        \
        asm volatile("s_waitcnt lgkmcnt(0)" ::: "memory");                       \
        __builtin_amdgcn_s_barrier();                                            \
    }

    for (int c = 0; c < NCH; c += 2) {
        CHUNK(c, A0);
        CHUNK(c + 1, A1);
    }
#undef CHUNK

    // epilogue: D layout col=lane&15 (o), row=quad*4+r (i-local); accL[r]=denom
    float* outp = out + ((long)b * NN + rowbase) * FO;
#pragma unroll
    for (int r = 0; r < 4; ++r) {
        int orow = quad * 4 + r;
        float inv = 1.0f / accL[r];
#pragma unroll
        for (int ot = 0; ot < 4; ++ot) {
            outp[(long)orow * FO + ot * 16 + m] = acc[ot][r] * inv;
        }
    }
}

extern "C" void kernel_launch(void* const* d_in, const int* in_sizes, int n_in,
                              void* d_out, int out_size, void* d_ws, size_t ws_size,
                              hipStream_t stream) {
    const float* x      = (const float*)d_in[0];
    const int*   adj    = (const int*)d_in[1];
    const float* weight = (const float*)d_in[2];
    const float* w2     = (const float*)d_in[3];
    float* out = (float*)d_out;

    char* ws = (char*)d_ws;
    __bf16* hT   = (__bf16*)ws;                              // 4 MB
    float* s_src = (float*)(ws + 4194304);                   // 128 KB
    float* s_dst = (float*)(ws + 4194304 + 131072);          // 128 KB

    k1_gemm<<<512, 256, 0, stream>>>(x, weight, w2, hT, s_src, s_dst);
    k2_attn<<<512, 256, 0, stream>>>(adj, s_src, s_dst, hT, out);
}